// Round 1
// baseline (2329.548 us; speedup 1.0000x reference)
//
#include <hip/hip_runtime.h>
#include <math.h>

#define NB 4096
#define IN_D 230
#define DM 256
#define NL 12
#define DST 16
#define DI 512
#define DTR 16
#define XPN 48  // DTR + 2*DST

__device__ __forceinline__ float silu_f(float x) { return x / (1.0f + expf(-x)); }
__device__ __forceinline__ float softplus_f(float x) { return (x > 20.0f) ? x : log1pf(expf(x)); }

// Generic tiled fp32 GEMM: C[M,N] = A[M,K] @ W[K,N] (+bias) with optional epilogue.
// EPI=0: plain (+bias if non-null) -> C
// EPI=1: in_proj split: col<512 -> C(xc) = silu(v*cw[col*4+3]+cb[col]); col>=512 -> out2(sz) = silu(v)
template <int EPI>
__global__ __launch_bounds__(256) void gemm64(
    const float* __restrict__ A, const float* __restrict__ W,
    const float* __restrict__ bias, float* __restrict__ C,
    int M, int N, int K,
    const float* __restrict__ cw, const float* __restrict__ cb,
    float* __restrict__ out2)
{
    __shared__ float As[16][68];
    __shared__ float Bs[16][68];
    const int tid = threadIdx.x;
    const int tx = tid & 15, ty = tid >> 4;
    const int rowBase = blockIdx.y * 64, colBase = blockIdx.x * 64;

    float acc[4][4] = {};

    const int aRow = tid >> 2;          // 0..63
    const int aColB = (tid & 3) * 4;    // 0,4,8,12
    const int bRow = tid >> 4;          // 0..15
    const int bColB = (tid & 15) * 4;   // 0..60

    for (int kk = 0; kk < K; kk += 16) {
#pragma unroll
        for (int i = 0; i < 4; i++) {
            int k = aColB + i;
            int r = rowBase + aRow;
            float v = 0.0f;
            if (r < M && (kk + k) < K) v = A[(size_t)r * K + kk + k];
            As[k][aRow] = v;
        }
#pragma unroll
        for (int i = 0; i < 4; i++) {
            int c = bColB + i;
            float v = 0.0f;
            if ((kk + bRow) < K && (colBase + c) < N) v = W[(size_t)(kk + bRow) * N + colBase + c];
            Bs[bRow][c] = v;
        }
        __syncthreads();
#pragma unroll
        for (int k = 0; k < 16; k++) {
            float a0 = As[k][ty * 4 + 0], a1 = As[k][ty * 4 + 1];
            float a2 = As[k][ty * 4 + 2], a3 = As[k][ty * 4 + 3];
            float b0 = Bs[k][tx * 4 + 0], b1 = Bs[k][tx * 4 + 1];
            float b2 = Bs[k][tx * 4 + 2], b3 = Bs[k][tx * 4 + 3];
            acc[0][0] += a0 * b0; acc[0][1] += a0 * b1; acc[0][2] += a0 * b2; acc[0][3] += a0 * b3;
            acc[1][0] += a1 * b0; acc[1][1] += a1 * b1; acc[1][2] += a1 * b2; acc[1][3] += a1 * b3;
            acc[2][0] += a2 * b0; acc[2][1] += a2 * b1; acc[2][2] += a2 * b2; acc[2][3] += a2 * b3;
            acc[3][0] += a3 * b0; acc[3][1] += a3 * b1; acc[3][2] += a3 * b2; acc[3][3] += a3 * b3;
        }
        __syncthreads();
    }

#pragma unroll
    for (int i = 0; i < 4; i++) {
        int row = rowBase + ty * 4 + i;
        if (row >= M) continue;
#pragma unroll
        for (int j = 0; j < 4; j++) {
            int col = colBase + tx * 4 + j;
            if (col >= N) continue;
            float v = acc[i][j];
            if (EPI == 0) {
                if (bias) v += bias[col];
                C[(size_t)row * N + col] = v;
            } else {
                // in_proj epilogue: N==1024, first 512 cols -> xc, last 512 -> silu(z)
                if (col < DI) {
                    C[(size_t)row * DI + col] = silu_f(v * cw[col * 4 + 3] + cb[col]);
                } else {
                    out2[(size_t)row * DI + (col - DI)] = silu_f(v);
                }
            }
        }
    }
}

// Per-row: dt = softplus(dbl[:,0:16] @ dt_w + dt_b); bc = Bm.Cm;
// y = (dt*bc + D) * xc * silu(z)
__global__ __launch_bounds__(256) void state_step(
    const float* __restrict__ dbl, const float* __restrict__ dtw,
    const float* __restrict__ dtb, const float* __restrict__ Dv,
    const float* __restrict__ xc, const float* __restrict__ sz,
    float* __restrict__ y)
{
    const int row = blockIdx.x;
    const int tid = threadIdx.x;
    __shared__ float sd[XPN];
    __shared__ float sbc;
    if (tid < XPN) sd[tid] = dbl[(size_t)row * XPN + tid];
    __syncthreads();
    if (tid == 0) {
        float bc = 0.0f;
#pragma unroll
        for (int s = 0; s < DST; s++) bc += sd[DTR + s] * sd[DTR + DST + s];
        sbc = bc;
    }
    __syncthreads();
    const float bc = sbc;
#pragma unroll
    for (int dd = 0; dd < 2; dd++) {
        int d = tid + dd * 256;
        float acc = dtb[d];
#pragma unroll
        for (int r = 0; r < DTR; r++) acc += sd[r] * dtw[r * DI + d];
        float dt = softplus_f(acc);
        float v = (dt * bc + Dv[d]) * xc[(size_t)row * DI + d] * sz[(size_t)row * DI + d];
        y[(size_t)row * DI + d] = v;
    }
}

// out[row] = dot(h[row,:], Wo) + bo  (one wave per row)
__global__ __launch_bounds__(64) void final_out(
    const float* __restrict__ h, const float* __restrict__ Wo,
    const float* __restrict__ bo, float* __restrict__ out)
{
    const int row = blockIdx.x;
    const int lane = threadIdx.x;
    float s = 0.0f;
#pragma unroll
    for (int c = lane; c < DM; c += 64) s += h[(size_t)row * DM + c] * Wo[c];
#pragma unroll
    for (int off = 32; off > 0; off >>= 1) s += __shfl_down(s, off);
    if (lane == 0) out[row] = s + bo[0];
}

extern "C" void kernel_launch(void* const* d_in, const int* in_sizes, int n_in,
                              void* d_out, int out_size, void* d_ws, size_t ws_size,
                              hipStream_t stream)
{
    const float* x       = (const float*)d_in[0];
    const float* Wi      = (const float*)d_in[1];
    const float* bi      = (const float*)d_in[2];
    const float* in_proj = (const float*)d_in[3];
    const float* conv_w  = (const float*)d_in[4];
    const float* conv_b  = (const float*)d_in[5];
    const float* x_proj  = (const float*)d_in[6];
    const float* dt_w    = (const float*)d_in[7];
    const float* dt_b    = (const float*)d_in[8];
    // d_in[9] = A_log: dead (h0 == 0, L == 1)
    const float* Dp      = (const float*)d_in[10];
    const float* out_pw  = (const float*)d_in[11];
    const float* Wo      = (const float*)d_in[12];
    const float* bo      = (const float*)d_in[13];

    float* ws  = (float*)d_ws;
    float* h   = ws;                        // 4096*256
    float* xc  = h + (size_t)NB * DM;       // 4096*512
    float* sz  = xc + (size_t)NB * DI;      // 4096*512
    float* dbl = sz + (size_t)NB * DI;      // 4096*48
    float* y   = dbl + (size_t)NB * XPN;    // 4096*512

    dim3 blk(256);

    // h = x @ Wi + bi   (M=4096, N=256, K=230)
    gemm64<0><<<dim3(DM / 64, NB / 64), blk, 0, stream>>>(
        x, Wi, bi, h, NB, DM, IN_D, nullptr, nullptr, nullptr);

    for (int l = 0; l < NL; l++) {
        const float* ip  = in_proj + (size_t)l * DM * 2 * DI;
        const float* cw  = conv_w + (size_t)l * DI * 4;
        const float* cb  = conv_b + (size_t)l * DI;
        const float* xp  = x_proj + (size_t)l * DI * XPN;
        const float* dtw = dt_w + (size_t)l * DTR * DI;
        const float* dtb = dt_b + (size_t)l * DI;
        const float* Dv  = Dp + (size_t)l * DI;
        const float* op  = out_pw + (size_t)l * DI * DM;

        // xz = h @ in_proj; xc = silu(xr*cw3+cb); sz = silu(z)
        gemm64<1><<<dim3(2 * DI / 64, NB / 64), blk, 0, stream>>>(
            h, ip, nullptr, xc, NB, 2 * DI, DM, cw, cb, sz);

        // dbl = xc @ x_proj  (N=48)
        gemm64<0><<<dim3(1, NB / 64), blk, 0, stream>>>(
            xc, xp, nullptr, dbl, NB, XPN, DI, nullptr, nullptr, nullptr);

        // y = (softplus(dt@dtw+dtb)*bc + D) * xc * silu(z)
        state_step<<<dim3(NB), blk, 0, stream>>>(dbl, dtw, dtb, Dv, xc, sz, y);

        // h = y @ out_proj  (N=256, K=512)
        gemm64<0><<<dim3(DM / 64, NB / 64), blk, 0, stream>>>(
            y, op, nullptr, h, NB, DM, DI, nullptr, nullptr, nullptr);
    }

    final_out<<<dim3(NB), dim3(64), 0, stream>>>(h, Wo, bo, (float*)d_out);
}

// Round 2
// 1592.721 us; speedup vs baseline: 1.4626x; 1.4626x over previous
//
#include <hip/hip_runtime.h>
#include <math.h>

#define NB 4096
#define IN_D 230
#define DM 256
#define NL 12
#define DST 16
#define DI 512
#define DTR 16
#define XPN 48
#define BK 32
#define LDST 40  // padded LDS row stride (elements)

typedef __attribute__((ext_vector_type(8))) short short8;
typedef __attribute__((ext_vector_type(4))) float floatx4;

__device__ __forceinline__ float silu_f(float x) { return x / (1.0f + expf(-x)); }
__device__ __forceinline__ float softplus_f(float x) { return (x > 20.0f) ? x : log1pf(expf(x)); }
__device__ __forceinline__ short f2bf(float x) {
    union { float f; unsigned u; } v; v.f = x;
    unsigned r = v.u + 0x7fff + ((v.u >> 16) & 1);
    return (short)(r >> 16);
}
__device__ __forceinline__ float bf2f(short s) {
    union { unsigned u; float f; } v; v.u = ((unsigned)(unsigned short)s) << 16;
    return v.f;
}

// ---------- conversion kernels (once per call) ----------

// x [4096 x 230] fp32 -> xpad [4096 x 256] bf16 (zero-padded K)
__global__ __launch_bounds__(256) void conv_x(const float* __restrict__ x, short* __restrict__ xp) {
    int idx = blockIdx.x * 256 + threadIdx.x;          // over 4096*256
    int r = idx >> 8, k = idx & 255;
    float v = (k < IN_D) ? x[(size_t)r * IN_D + k] : 0.0f;
    xp[idx] = f2bf(v);
}

// in [K x N] fp32 -> out [N x Kp] bf16 (transpose + pad K->Kp), batched over layers
__global__ __launch_bounds__(256) void conv_wt(const float* __restrict__ in, short* __restrict__ out,
                                               int K, int N, int Kp) {
    int l = blockIdx.y;
    const float* src = in + (size_t)l * K * N;
    short* dst = out + (size_t)l * N * Kp;
    int idx = blockIdx.x * 256 + threadIdx.x;          // over N*Kp
    int n = idx / Kp, k = idx - n * Kp;                // consecutive tid -> consecutive k (coalesced writes)
    float v = (k < K) ? src[(size_t)k * N + n] : 0.0f;
    dst[idx] = f2bf(v);
}

// ---------- MFMA GEMM ----------
// C[M,N] = A[M,K](bf16) @ Bt[N,K](bf16)^T, fp32 accum.
// EPI 0: (+bias) -> C0 bf16.  EPI 1: in_proj split epilogue.
template <int BM, int BN, int EPI>
__global__ __launch_bounds__(256) void gemm_mfma(
    const short* __restrict__ A, const short* __restrict__ Bt,
    const float* __restrict__ bias,
    short* __restrict__ C0, short* __restrict__ C1,
    const float* __restrict__ cw, const float* __restrict__ cb,
    int M, int N, int K)
{
    constexpr int WM = BM / 2, WN = BN / 2;
    constexpr int MI = WM / 16, NI = WN / 16;
    __shared__ short As[BM * LDST];
    __shared__ short Bs[BN * LDST];
    const int tid = threadIdx.x;
    const int wave = tid >> 6, lane = tid & 63;
    const int wr = wave >> 1, wc = wave & 1;
    const int q = lane >> 4, m16 = lane & 15;
    const int rowBase = blockIdx.y * BM, colBase = blockIdx.x * BN;

    floatx4 acc[MI][NI];
#pragma unroll
    for (int i = 0; i < MI; i++)
#pragma unroll
        for (int j = 0; j < NI; j++) acc[i][j] = (floatx4){0.f, 0.f, 0.f, 0.f};

    for (int kk = 0; kk < K; kk += BK) {
#pragma unroll
        for (int it = 0; it < (BM * BK) / 2048; ++it) {
            int idx = it * 2048 + tid * 8;
            int r = idx >> 5, k = idx & 31;
            short8 v = *(const short8*)(A + (size_t)(rowBase + r) * K + kk + k);
            *(short8*)(&As[r * LDST + k]) = v;
        }
#pragma unroll
        for (int it = 0; it < (BN * BK) / 2048; ++it) {
            int idx = it * 2048 + tid * 8;
            int r = idx >> 5, k = idx & 31;
            short8 v = *(const short8*)(Bt + (size_t)(colBase + r) * K + kk + k);
            *(short8*)(&Bs[r * LDST + k]) = v;
        }
        __syncthreads();
        short8 aF[MI], bF[NI];
#pragma unroll
        for (int mi = 0; mi < MI; ++mi)
            aF[mi] = *(const short8*)(&As[(wr * WM + mi * 16 + m16) * LDST + q * 8]);
#pragma unroll
        for (int ni = 0; ni < NI; ++ni)
            bF[ni] = *(const short8*)(&Bs[(wc * WN + ni * 16 + m16) * LDST + q * 8]);
#pragma unroll
        for (int mi = 0; mi < MI; ++mi)
#pragma unroll
            for (int ni = 0; ni < NI; ++ni)
                acc[mi][ni] = __builtin_amdgcn_mfma_f32_16x16x32_bf16(aF[mi], bF[ni], acc[mi][ni], 0, 0, 0);
        __syncthreads();
    }

#pragma unroll
    for (int mi = 0; mi < MI; ++mi)
#pragma unroll
        for (int ni = 0; ni < NI; ++ni)
#pragma unroll
            for (int r = 0; r < 4; ++r) {
                int row = rowBase + wr * WM + mi * 16 + q * 4 + r;
                int col = colBase + wc * WN + ni * 16 + m16;
                float v = acc[mi][ni][r];
                if (EPI == 0) {
                    if (bias) v += bias[col];
                    C0[(size_t)row * N + col] = f2bf(v);
                } else {
                    if (col < DI) {
                        C0[(size_t)row * DI + col] = f2bf(silu_f(v * cw[col * 4 + 3] + cb[col]));
                    } else {
                        C1[(size_t)row * DI + (col - DI)] = f2bf(silu_f(v));
                    }
                }
            }
}

// ---------- fused x_proj + dt_proj + state + gating ----------
// 4 rows per block. dbl = xc@x_proj; bc = B.C; dt = softplus(dbl[:16]@dtw + dtb);
// y = (dt*bc + D) * xc * sz   (all bf16 in/out, fp32 math)
__global__ __launch_bounds__(256) void state_fused(
    const short* __restrict__ xc, const short* __restrict__ sz,
    const float* __restrict__ xp, const float* __restrict__ dtw,
    const float* __restrict__ dtb, const float* __restrict__ Dv,
    short* __restrict__ y)
{
    const int tid = threadIdx.x;
    const int rb = blockIdx.x * 4;
    __shared__ float sxc[4][DI];
    __shared__ float sd[4][XPN];
    __shared__ float sbc[4];

    {   // load 4 rows of xc -> LDS fp32
        int row = tid >> 6, k = (tid & 63) * 8;
        short8 v = *(const short8*)(xc + (size_t)(rb + row) * DI + k);
#pragma unroll
        for (int i = 0; i < 8; i++) sxc[row][k + i] = bf2f(v[i]);
    }
    __syncthreads();

    if (tid < 4 * XPN) {
        int row = tid / XPN, j = tid - row * XPN;
        float s = 0.0f;
        for (int k = 0; k < DI; k++) s += sxc[row][k] * xp[k * XPN + j];
        sd[row][j] = s;
    }
    __syncthreads();
    if (tid < 4) {
        float bc = 0.0f;
#pragma unroll
        for (int s = 0; s < DST; s++) bc += sd[tid][DTR + s] * sd[tid][DTR + DST + s];
        sbc[tid] = bc;
    }
    __syncthreads();

    {
        int row = tid >> 6, k0 = (tid & 63) * 8;
        short8 zs = *(const short8*)(sz + (size_t)(rb + row) * DI + k0);
        short8 out;
        float bc = sbc[row];
#pragma unroll
        for (int i = 0; i < 8; i++) {
            int d = k0 + i;
            float a = dtb[d];
#pragma unroll
            for (int r = 0; r < DTR; r++) a += sd[row][r] * dtw[r * DI + d];
            float dt = softplus_f(a);
            float v = (dt * bc + Dv[d]) * sxc[row][d] * bf2f(zs[i]);
            out[i] = f2bf(v);
        }
        *(short8*)(y + (size_t)(rb + row) * DI + k0) = out;
    }
}

// out[row] = dot(h[row,:], Wo) + bo   (wave per row, 4 rows/block)
__global__ __launch_bounds__(256) void final_out(
    const short* __restrict__ h, const float* __restrict__ Wo,
    const float* __restrict__ bo, float* __restrict__ out)
{
    const int row = blockIdx.x * 4 + (threadIdx.x >> 6);
    const int lane = threadIdx.x & 63;
    float s = 0.0f;
#pragma unroll
    for (int i = 0; i < 4; i++) {
        int c = lane * 4 + i;
        s += bf2f(h[(size_t)row * DM + c]) * Wo[c];
    }
#pragma unroll
    for (int off = 32; off > 0; off >>= 1) s += __shfl_down(s, off);
    if (lane == 0) out[row] = s + bo[0];
}

extern "C" void kernel_launch(void* const* d_in, const int* in_sizes, int n_in,
                              void* d_out, int out_size, void* d_ws, size_t ws_size,
                              hipStream_t stream)
{
    const float* x       = (const float*)d_in[0];
    const float* Wi      = (const float*)d_in[1];
    const float* bi      = (const float*)d_in[2];
    const float* in_proj = (const float*)d_in[3];
    const float* conv_w  = (const float*)d_in[4];
    const float* conv_b  = (const float*)d_in[5];
    const float* x_proj  = (const float*)d_in[6];
    const float* dt_w    = (const float*)d_in[7];
    const float* dt_b    = (const float*)d_in[8];
    // d_in[9] = A_log: dead (L==1, h0==0)
    const float* Dp      = (const float*)d_in[10];
    const float* out_pw  = (const float*)d_in[11];
    const float* Wo      = (const float*)d_in[12];
    const float* bo      = (const float*)d_in[13];

    short* ws   = (short*)d_ws;
    short* xpad = ws;                                   // 4096*256
    short* WiT  = xpad + (size_t)NB * DM;               // 256*256
    short* ipT  = WiT + (size_t)DM * DM;                // 12*1024*256
    short* opT  = ipT + (size_t)NL * 2 * DI * DM;       // 12*256*512
    short* h    = opT + (size_t)NL * DM * DI;           // 4096*256
    short* xc   = h + (size_t)NB * DM;                  // 4096*512
    short* szb  = xc + (size_t)NB * DI;                 // 4096*512
    short* y    = szb + (size_t)NB * DI;                // 4096*512

    dim3 blk(256);

    // one-time converts
    conv_x<<<dim3(NB * DM / 256), blk, 0, stream>>>(x, xpad);
    conv_wt<<<dim3(DM * DM / 256, 1), blk, 0, stream>>>(Wi, WiT, IN_D, DM, DM);
    conv_wt<<<dim3(2 * DI * DM / 256, NL), blk, 0, stream>>>(in_proj, ipT, DM, 2 * DI, DM);
    conv_wt<<<dim3(DM * DI / 256, NL), blk, 0, stream>>>(out_pw, opT, DI, DM, DI);

    // h = x @ Wi + bi  (M=4096,N=256,K=256 padded)
    gemm_mfma<128, 64, 0><<<dim3(DM / 64, NB / 128), blk, 0, stream>>>(
        xpad, WiT, bi, h, nullptr, nullptr, nullptr, NB, DM, DM);

    for (int l = 0; l < NL; l++) {
        const short* ip  = ipT + (size_t)l * 2 * DI * DM;
        const short* op  = opT + (size_t)l * DM * DI;
        const float* cw  = conv_w + (size_t)l * DI * 4;
        const float* cb  = conv_b + (size_t)l * DI;
        const float* xpw = x_proj + (size_t)l * DI * XPN;
        const float* dtw = dt_w + (size_t)l * DTR * DI;
        const float* dtb = dt_b + (size_t)l * DI;
        const float* Dv  = Dp + (size_t)l * DI;

        // xz = h @ in_proj; xc = silu(conv); sz = silu(z)
        gemm_mfma<128, 128, 1><<<dim3(2 * DI / 128, NB / 128), blk, 0, stream>>>(
            h, ip, nullptr, xc, szb, cw, cb, NB, 2 * DI, DM);

        // dbl/dt/state/gating fused
        state_fused<<<dim3(NB / 4), blk, 0, stream>>>(xc, szb, xpw, dtw, dtb, Dv, y);

        // h = y @ out_proj  (N=256,K=512)
        gemm_mfma<128, 64, 0><<<dim3(DM / 64, NB / 128), blk, 0, stream>>>(
            y, op, nullptr, h, nullptr, nullptr, nullptr, NB, DM, DI);
    }

    final_out<<<dim3(NB / 4), blk, 0, stream>>>(h, Wo, bo, (float*)d_out);
}

// Round 3
// 829.417 us; speedup vs baseline: 2.8087x; 1.9203x over previous
//
#include <hip/hip_runtime.h>
#include <math.h>

#define NB 4096
#define IN_D 230
#define DM 256
#define NL 12
#define DST 16
#define DI 512
#define DTR 16
#define XPN 48
#define XPNP 64   // padded N for the dbl gemm
#define BK 32
#define LDST 40   // padded LDS row stride (elements)

typedef __attribute__((ext_vector_type(8))) short short8;
typedef __attribute__((ext_vector_type(4))) float floatx4;

__device__ __forceinline__ float silu_f(float x) { return x / (1.0f + expf(-x)); }
__device__ __forceinline__ float softplus_f(float x) { return (x > 20.0f) ? x : log1pf(expf(x)); }
__device__ __forceinline__ short f2bf(float x) {
    union { float f; unsigned u; } v; v.f = x;
    unsigned r = v.u + 0x7fff + ((v.u >> 16) & 1);
    return (short)(r >> 16);
}
__device__ __forceinline__ float bf2f(short s) {
    union { unsigned u; float f; } v; v.u = ((unsigned)(unsigned short)s) << 16;
    return v.f;
}

// ---------- conversion kernels (once per call) ----------

// x [4096 x 230] fp32 -> xpad [4096 x 256] bf16 (zero-padded K)
__global__ __launch_bounds__(256) void conv_x(const float* __restrict__ x, short* __restrict__ xp) {
    int idx = blockIdx.x * 256 + threadIdx.x;
    int r = idx >> 8, k = idx & 255;
    float v = (k < IN_D) ? x[(size_t)r * IN_D + k] : 0.0f;
    xp[idx] = f2bf(v);
}

// Tiled transpose-convert: src [K x N] fp32 -> dst [Np x Kp] bf16 (dst[n][k]=src[k][n], zero-pad).
// Kp, Np multiples of 64. grid = (Kp/64, Np/64, L).
__global__ __launch_bounds__(256) void conv_wt_t(const float* __restrict__ src0, short* __restrict__ dst0,
                                                 int K, int N, int Kp, int Np) {
    const float* src = src0 + (size_t)blockIdx.z * K * N;
    short* dst = dst0 + (size_t)blockIdx.z * Np * Kp;
    __shared__ float t[64][65];
    const int k0 = blockIdx.x * 64, n0 = blockIdx.y * 64;
    const int r = threadIdx.x >> 6, c = threadIdx.x & 63;
#pragma unroll
    for (int i = 0; i < 16; i++) {
        int kk = k0 + i * 4 + r;
        int nn = n0 + c;
        float v = (kk < K && nn < N) ? src[(size_t)kk * N + nn] : 0.0f;
        t[i * 4 + r][c] = v;
    }
    __syncthreads();
#pragma unroll
    for (int i = 0; i < 16; i++) {
        int nn = n0 + i * 4 + r;          // dst row (n)
        int kk = k0 + c;                  // dst col (k)
        dst[(size_t)nn * Kp + kk] = f2bf(t[c][i * 4 + r]);
    }
}

// ---------- MFMA GEMM ----------
// C[M,N] = A[M,K](bf16) @ Bt[N,K](bf16)^T, fp32 accum.
// EPI 0: (+bias) -> C0 bf16.  EPI 1: in_proj split epilogue.  EPI 2: plain -> fp32.
template <int BM, int BN, int EPI>
__global__ __launch_bounds__(256) void gemm_mfma(
    const short* __restrict__ A, const short* __restrict__ Bt,
    const float* __restrict__ bias,
    short* __restrict__ C0, short* __restrict__ C1,
    const float* __restrict__ cw, const float* __restrict__ cb,
    int M, int N, int K)
{
    constexpr int WM = BM / 2, WN = BN / 2;
    constexpr int MI = WM / 16, NI = WN / 16;
    __shared__ short As[BM * LDST];
    __shared__ short Bs[BN * LDST];
    const int tid = threadIdx.x;
    const int wave = tid >> 6, lane = tid & 63;
    const int wr = wave >> 1, wc = wave & 1;
    const int q = lane >> 4, m16 = lane & 15;
    const int rowBase = blockIdx.y * BM, colBase = blockIdx.x * BN;

    floatx4 acc[MI][NI];
#pragma unroll
    for (int i = 0; i < MI; i++)
#pragma unroll
        for (int j = 0; j < NI; j++) acc[i][j] = (floatx4){0.f, 0.f, 0.f, 0.f};

    for (int kk = 0; kk < K; kk += BK) {
#pragma unroll
        for (int it = 0; it < (BM * BK) / 2048; ++it) {
            int idx = it * 2048 + tid * 8;
            int r = idx >> 5, k = idx & 31;
            short8 v = *(const short8*)(A + (size_t)(rowBase + r) * K + kk + k);
            *(short8*)(&As[r * LDST + k]) = v;
        }
#pragma unroll
        for (int it = 0; it < (BN * BK) / 2048; ++it) {
            int idx = it * 2048 + tid * 8;
            int r = idx >> 5, k = idx & 31;
            short8 v = *(const short8*)(Bt + (size_t)(colBase + r) * K + kk + k);
            *(short8*)(&Bs[r * LDST + k]) = v;
        }
        __syncthreads();
        short8 aF[MI], bF[NI];
#pragma unroll
        for (int mi = 0; mi < MI; ++mi)
            aF[mi] = *(const short8*)(&As[(wr * WM + mi * 16 + m16) * LDST + q * 8]);
#pragma unroll
        for (int ni = 0; ni < NI; ++ni)
            bF[ni] = *(const short8*)(&Bs[(wc * WN + ni * 16 + m16) * LDST + q * 8]);
#pragma unroll
        for (int mi = 0; mi < MI; ++mi)
#pragma unroll
            for (int ni = 0; ni < NI; ++ni)
                acc[mi][ni] = __builtin_amdgcn_mfma_f32_16x16x32_bf16(aF[mi], bF[ni], acc[mi][ni], 0, 0, 0);
        __syncthreads();
    }

#pragma unroll
    for (int mi = 0; mi < MI; ++mi)
#pragma unroll
        for (int ni = 0; ni < NI; ++ni)
#pragma unroll
            for (int r = 0; r < 4; ++r) {
                int row = rowBase + wr * WM + mi * 16 + q * 4 + r;
                int col = colBase + wc * WN + ni * 16 + m16;
                float v = acc[mi][ni][r];
                if (EPI == 0) {
                    if (bias) v += bias[col];
                    C0[(size_t)row * N + col] = f2bf(v);
                } else if (EPI == 1) {
                    if (col < DI) {
                        C0[(size_t)row * DI + col] = f2bf(silu_f(v * cw[col * 4 + 3] + cb[col]));
                    } else {
                        C1[(size_t)row * DI + (col - DI)] = f2bf(silu_f(v));
                    }
                } else {
                    ((float*)C0)[(size_t)row * N + col] = v;
                }
            }
}

// ---------- elementwise state + gating ----------
// 4 rows/block. bc = dbl[16:32].dbl[32:48]; dt = softplus(dbl[:16]@dtw + dtb);
// y = (dt*bc + D) * xc * sz
__global__ __launch_bounds__(256) void state_ew(
    const float* __restrict__ dbl,   // [NB x 64] fp32
    const short* __restrict__ xc, const short* __restrict__ sz,
    const float* __restrict__ dtw, const float* __restrict__ dtb,
    const float* __restrict__ Dv, short* __restrict__ y)
{
    const int tid = threadIdx.x;
    const int rb = blockIdx.x * 4;
    __shared__ float sdl[4][XPN];
    __shared__ float sbc[4];

    if (tid < 4 * XPN) {
        int row = tid / XPN, j = tid - row * XPN;
        sdl[row][j] = dbl[(size_t)(rb + row) * XPNP + j];
    }
    __syncthreads();
    if (tid < 4) {
        float bc = 0.0f;
#pragma unroll
        for (int s = 0; s < DST; s++) bc += sdl[tid][DTR + s] * sdl[tid][DTR + DST + s];
        sbc[tid] = bc;
    }
    __syncthreads();

#pragma unroll
    for (int half = 0; half < 2; half++) {
        const int d = half * 256 + tid;
        float w[DTR];
#pragma unroll
        for (int r = 0; r < DTR; r++) w[r] = dtw[r * DI + d];
        const float db = dtb[d], dv = Dv[d];
#pragma unroll
        for (int row = 0; row < 4; row++) {
            float a = db;
#pragma unroll
            for (int r = 0; r < DTR; r++) a += sdl[row][r] * w[r];
            float dt = softplus_f(a);
            size_t off = (size_t)(rb + row) * DI + d;
            float v = (dt * sbc[row] + dv) * bf2f(xc[off]) * bf2f(sz[off]);
            y[off] = f2bf(v);
        }
    }
}

// out[row] = dot(h[row,:], Wo) + bo   (wave per row, 4 rows/block)
__global__ __launch_bounds__(256) void final_out(
    const short* __restrict__ h, const float* __restrict__ Wo,
    const float* __restrict__ bo, float* __restrict__ out)
{
    const int row = blockIdx.x * 4 + (threadIdx.x >> 6);
    const int lane = threadIdx.x & 63;
    float s = 0.0f;
#pragma unroll
    for (int i = 0; i < 4; i++) {
        int c = lane * 4 + i;
        s += bf2f(h[(size_t)row * DM + c]) * Wo[c];
    }
#pragma unroll
    for (int off = 32; off > 0; off >>= 1) s += __shfl_down(s, off);
    if (lane == 0) out[row] = s + bo[0];
}

extern "C" void kernel_launch(void* const* d_in, const int* in_sizes, int n_in,
                              void* d_out, int out_size, void* d_ws, size_t ws_size,
                              hipStream_t stream)
{
    const float* x       = (const float*)d_in[0];
    const float* Wi      = (const float*)d_in[1];
    const float* bi      = (const float*)d_in[2];
    const float* in_proj = (const float*)d_in[3];
    const float* conv_w  = (const float*)d_in[4];
    const float* conv_b  = (const float*)d_in[5];
    const float* x_proj  = (const float*)d_in[6];
    const float* dt_w    = (const float*)d_in[7];
    const float* dt_b    = (const float*)d_in[8];
    // d_in[9] = A_log: dead (L==1, h0==0)
    const float* Dp      = (const float*)d_in[10];
    const float* out_pw  = (const float*)d_in[11];
    const float* Wo      = (const float*)d_in[12];
    const float* bo      = (const float*)d_in[13];

    short* ws   = (short*)d_ws;
    short* xpad = ws;                                   // 4096*256
    short* WiT  = xpad + (size_t)NB * DM;               // 256*256
    short* ipT  = WiT + (size_t)DM * DM;                // 12*1024*256
    short* opT  = ipT + (size_t)NL * 2 * DI * DM;       // 12*256*512
    short* xpT  = opT + (size_t)NL * DM * DI;           // 12*64*512
    short* h    = xpT + (size_t)NL * XPNP * DI;         // 4096*256
    short* xc   = h + (size_t)NB * DM;                  // 4096*512
    short* szb  = xc + (size_t)NB * DI;                 // 4096*512
    short* y    = szb + (size_t)NB * DI;                // 4096*512
    float* dbl  = (float*)(y + (size_t)NB * DI);        // 4096*64 fp32

    dim3 blk(256);

    // one-time converts
    conv_x<<<dim3(NB * DM / 256), blk, 0, stream>>>(x, xpad);
    conv_wt_t<<<dim3(4, 4, 1), blk, 0, stream>>>(Wi, WiT, IN_D, DM, DM, DM);
    conv_wt_t<<<dim3(4, 16, NL), blk, 0, stream>>>(in_proj, ipT, DM, 2 * DI, DM, 2 * DI);
    conv_wt_t<<<dim3(8, 4, NL), blk, 0, stream>>>(out_pw, opT, DI, DM, DI, DM);
    conv_wt_t<<<dim3(8, 1, NL), blk, 0, stream>>>(x_proj, xpT, DI, XPN, DI, XPNP);

    // h = x @ Wi + bi  (M=4096,N=256,K=256 padded)
    gemm_mfma<128, 64, 0><<<dim3(DM / 64, NB / 128), blk, 0, stream>>>(
        xpad, WiT, bi, h, nullptr, nullptr, nullptr, NB, DM, DM);

    for (int l = 0; l < NL; l++) {
        const short* ip  = ipT + (size_t)l * 2 * DI * DM;
        const short* op  = opT + (size_t)l * DM * DI;
        const short* xp  = xpT + (size_t)l * XPNP * DI;
        const float* cw  = conv_w + (size_t)l * DI * 4;
        const float* cb  = conv_b + (size_t)l * DI;
        const float* dtw = dt_w + (size_t)l * DTR * DI;
        const float* dtb = dt_b + (size_t)l * DI;
        const float* Dv  = Dp + (size_t)l * DI;

        // xz = h @ in_proj; xc = silu(conv); sz = silu(z)
        gemm_mfma<128, 128, 1><<<dim3(2 * DI / 128, NB / 128), blk, 0, stream>>>(
            h, ip, nullptr, xc, szb, cw, cb, NB, 2 * DI, DM);

        // dbl = xc @ x_proj  (N=64 padded, K=512, fp32 out)
        gemm_mfma<128, 64, 2><<<dim3(1, NB / 128), blk, 0, stream>>>(
            xc, xp, nullptr, (short*)dbl, nullptr, nullptr, nullptr, NB, XPNP, DI);

        // dt/state/gating
        state_ew<<<dim3(NB / 4), blk, 0, stream>>>(dbl, xc, szb, dtw, dtb, Dv, y);

        // h = y @ out_proj  (N=256,K=512)
        gemm_mfma<128, 64, 0><<<dim3(DM / 64, NB / 128), blk, 0, stream>>>(
            y, op, nullptr, h, nullptr, nullptr, nullptr, NB, DM, DI);
    }

    final_out<<<dim3(NB / 4), blk, 0, stream>>>(h, Wo, bo, (float*)d_out);
}

// Round 4
// 773.916 us; speedup vs baseline: 3.0101x; 1.0717x over previous
//
#include <hip/hip_runtime.h>
#include <math.h>

#define NB 4096
#define IN_D 230
#define DM 256
#define NL 12
#define DST 16
#define DI 512
#define DTR 16
#define XPN 48

typedef __attribute__((ext_vector_type(8))) short short8;
typedef __attribute__((ext_vector_type(4))) float floatx4;

__device__ __forceinline__ float silu_f(float x) { return x / (1.0f + expf(-x)); }
__device__ __forceinline__ float softplus_f(float x) { return (x > 20.0f) ? x : log1pf(expf(x)); }
__device__ __forceinline__ short f2bf(float x) {
    union { float f; unsigned u; } v; v.f = x;
    unsigned r = v.u + 0x7fff + ((v.u >> 16) & 1);
    return (short)(r >> 16);
}
__device__ __forceinline__ float bf2f(short s) {
    union { unsigned u; float f; } v; v.u = ((unsigned)(unsigned short)s) << 16;
    return v.f;
}

// ---------- conversion kernels (once per call) ----------

__global__ __launch_bounds__(256) void conv_x(const float* __restrict__ x, short* __restrict__ xp) {
    int idx = blockIdx.x * 256 + threadIdx.x;
    int r = idx >> 8, k = idx & 255;
    float v = (k < IN_D) ? x[(size_t)r * IN_D + k] : 0.0f;
    xp[idx] = f2bf(v);
}

// src [K x N] fp32 -> dst [Np x Kp] bf16 (dst[n][k]=src[k][n], zero-pad)
__global__ __launch_bounds__(256) void conv_wt_t(const float* __restrict__ src0, short* __restrict__ dst0,
                                                 int K, int N, int Kp, int Np) {
    const float* src = src0 + (size_t)blockIdx.z * K * N;
    short* dst = dst0 + (size_t)blockIdx.z * Np * Kp;
    __shared__ float t[64][65];
    const int k0 = blockIdx.x * 64, n0 = blockIdx.y * 64;
    const int r = threadIdx.x >> 6, c = threadIdx.x & 63;
#pragma unroll
    for (int i = 0; i < 16; i++) {
        int kk = k0 + i * 4 + r;
        int nn = n0 + c;
        float v = (kk < K && nn < N) ? src[(size_t)kk * N + nn] : 0.0f;
        t[i * 4 + r][c] = v;
    }
    __syncthreads();
#pragma unroll
    for (int i = 0; i < 16; i++) {
        int nn = n0 + i * 4 + r;
        int kk = k0 + c;
        dst[(size_t)nn * Kp + kk] = f2bf(t[c][i * 4 + r]);
    }
}

// dt_w [NL][16][512] fp32 -> dtwT [NL][512][16] fp32
__global__ __launch_bounds__(256) void conv_dtw(const float* __restrict__ src, float* __restrict__ dst) {
    int l = blockIdx.y;
    int idx = blockIdx.x * 256 + threadIdx.x;
    int d = idx >> 4, r = idx & 15;
    dst[(size_t)l * DI * DTR + idx] = src[(size_t)l * DTR * DI + r * DI + d];
}

// ---------- the whole network, fused ----------
__global__ __launch_bounds__(256, 1) void mamba_all(
    const short* __restrict__ xpad, const short* __restrict__ WiT,
    const float* __restrict__ bi,
    const short* __restrict__ ipT, const short* __restrict__ opT,
    const short* __restrict__ xpT, const float* __restrict__ dtwT,
    const float* __restrict__ conv_w, const float* __restrict__ conv_b,
    const float* __restrict__ dt_b, const float* __restrict__ Dp,
    const float* __restrict__ Wo, const float* __restrict__ bo,
    float* __restrict__ out)
{
    __shared__ short hs[16 * 264];
    __shared__ short xcs[16 * 520];
    __shared__ short szs[16 * 520];
    __shared__ float dbls[16 * 68];
    __shared__ float sbc[16];
    __shared__ float partial[16 * 17];

    const int tid = threadIdx.x;
    const int wave = tid >> 6, lane = tid & 63;
    const int q = lane >> 4, m16 = lane & 15;
    const int rb = blockIdx.x * 16;

    // stage 0: h = xpad @ WiT + bi
    {
        floatx4 acc[4];
#pragma unroll
        for (int t = 0; t < 4; t++) acc[t] = (floatx4){0.f, 0.f, 0.f, 0.f};
        const short* Ap = xpad + (size_t)(rb + m16) * DM + q * 8;
        const short* Bp = WiT + (size_t)(wave * 64 + m16) * DM + q * 8;
        for (int kk = 0; kk < DM; kk += 32) {
            short8 a = *(const short8*)(Ap + kk);
            short8 b[4];
#pragma unroll
            for (int t = 0; t < 4; t++) b[t] = *(const short8*)(Bp + t * 16 * DM + kk);
#pragma unroll
            for (int t = 0; t < 4; t++)
                acc[t] = __builtin_amdgcn_mfma_f32_16x16x32_bf16(a, b[t], acc[t], 0, 0, 0);
        }
#pragma unroll
        for (int t = 0; t < 4; t++)
#pragma unroll
            for (int r = 0; r < 4; r++) {
                int col = wave * 64 + t * 16 + m16;
                hs[(q * 4 + r) * 264 + col] = f2bf(acc[t][r] + bi[col]);
            }
    }
    __syncthreads();

    for (int l = 0; l < NL; l++) {
        const short* ip = ipT + (size_t)l * 2 * DI * DM;
        const short* xp = xpT + (size_t)l * 64 * DI;
        const short* op = opT + (size_t)l * DM * DI;
        const float* dw = dtwT + (size_t)l * DI * DTR;
        const float* cw = conv_w + (size_t)l * DI * 4;
        const float* cb = conv_b + (size_t)l * DI;
        const float* db = dt_b + (size_t)l * DI;
        const float* Dv = Dp + (size_t)l * DI;

        // stage 1: xz = h @ in_projT; xc / sz epilogues
        {
            floatx4 acc[16];
#pragma unroll
            for (int t = 0; t < 16; t++) acc[t] = (floatx4){0.f, 0.f, 0.f, 0.f};
            const short* Bp = ip + (size_t)(wave * 256 + m16) * DM + q * 8;
            const short* Ar = hs + m16 * 264 + q * 8;
#pragma unroll 2
            for (int kk = 0; kk < DM; kk += 32) {
                short8 a = *(const short8*)(Ar + kk);
                short8 b[16];
#pragma unroll
                for (int t = 0; t < 16; t++) b[t] = *(const short8*)(Bp + (size_t)t * 16 * DM + kk);
#pragma unroll
                for (int t = 0; t < 16; t++)
                    acc[t] = __builtin_amdgcn_mfma_f32_16x16x32_bf16(a, b[t], acc[t], 0, 0, 0);
            }
            if (wave < 2) {
                int cbase = wave * 256;
#pragma unroll
                for (int t = 0; t < 16; t++)
#pragma unroll
                    for (int r = 0; r < 4; r++) {
                        int col = cbase + t * 16 + m16;
                        float v = silu_f(acc[t][r] * cw[col * 4 + 3] + cb[col]);
                        xcs[(q * 4 + r) * 520 + col] = f2bf(v);
                    }
            } else {
                int cbase = (wave - 2) * 256;
#pragma unroll
                for (int t = 0; t < 16; t++)
#pragma unroll
                    for (int r = 0; r < 4; r++) {
                        int col = cbase + t * 16 + m16;
                        szs[(q * 4 + r) * 520 + col] = f2bf(silu_f(acc[t][r]));
                    }
            }
        }
        __syncthreads();

        // stage 2: dbl = xc @ x_projT
        {
            floatx4 acc = (floatx4){0.f, 0.f, 0.f, 0.f};
            const short* Bp = xp + (size_t)(wave * 16 + m16) * DI + q * 8;
            const short* Ar = xcs + m16 * 520 + q * 8;
#pragma unroll 4
            for (int kk = 0; kk < DI; kk += 32) {
                short8 a = *(const short8*)(Ar + kk);
                short8 b = *(const short8*)(Bp + kk);
                acc = __builtin_amdgcn_mfma_f32_16x16x32_bf16(a, b, acc, 0, 0, 0);
            }
#pragma unroll
            for (int r = 0; r < 4; r++)
                dbls[(q * 4 + r) * 68 + wave * 16 + m16] = acc[r];
        }
        __syncthreads();

        if (tid < 16) {
            float bc = 0.0f;
#pragma unroll
            for (int s = 0; s < DST; s++)
                bc += dbls[tid * 68 + DTR + s] * dbls[tid * 68 + DTR + DST + s];
            sbc[tid] = bc;
        }
        __syncthreads();

        // stage 3: y = (softplus(dt)*bc + D) * xc * sz  (in place in xcs)
        {
#pragma unroll
            for (int dd = 0; dd < 2; dd++) {
                int d = tid * 2 + dd;
                const float* wp = dw + (size_t)d * DTR;
                float w[DTR];
#pragma unroll
                for (int r = 0; r < DTR; r++) w[r] = wp[r];
                float dbv = db[d], dvv = Dv[d];
#pragma unroll
                for (int row = 0; row < 16; row++) {
                    float a = dbv;
#pragma unroll
                    for (int r = 0; r < DTR; r++) a += dbls[row * 68 + r] * w[r];
                    float dt = softplus_f(a);
                    int off = row * 520 + d;
                    float v = (dt * sbc[row] + dvv) * bf2f(xcs[off]) * bf2f(szs[off]);
                    xcs[off] = f2bf(v);
                }
            }
        }
        __syncthreads();

        // stage 4: h = y @ out_projT
        {
            floatx4 acc[4];
#pragma unroll
            for (int t = 0; t < 4; t++) acc[t] = (floatx4){0.f, 0.f, 0.f, 0.f};
            const short* Bp = op + (size_t)(wave * 64 + m16) * DI + q * 8;
            const short* Ar = xcs + m16 * 520 + q * 8;
#pragma unroll 2
            for (int kk = 0; kk < DI; kk += 32) {
                short8 a = *(const short8*)(Ar + kk);
                short8 b[4];
#pragma unroll
                for (int t = 0; t < 4; t++) b[t] = *(const short8*)(Bp + (size_t)t * 16 * DI + kk);
#pragma unroll
                for (int t = 0; t < 4; t++)
                    acc[t] = __builtin_amdgcn_mfma_f32_16x16x32_bf16(a, b[t], acc[t], 0, 0, 0);
            }
#pragma unroll
            for (int t = 0; t < 4; t++)
#pragma unroll
                for (int r = 0; r < 4; r++) {
                    int col = wave * 64 + t * 16 + m16;
                    hs[(q * 4 + r) * 264 + col] = f2bf(acc[t][r]);
                }
        }
        __syncthreads();
    }

    // final: out[row] = h[row,:] . Wo + bo
    {
        int row = tid >> 4, c0 = (tid & 15) * 16;
        float s = 0.0f;
#pragma unroll
        for (int j = 0; j < 16; j++) s += bf2f(hs[row * 264 + c0 + j]) * Wo[c0 + j];
        partial[row * 17 + (tid & 15)] = s;
    }
    __syncthreads();
    if (tid < 16) {
        float o = bo[0];
#pragma unroll
        for (int j = 0; j < 16; j++) o += partial[tid * 17 + j];
        out[rb + tid] = o;
    }
}

extern "C" void kernel_launch(void* const* d_in, const int* in_sizes, int n_in,
                              void* d_out, int out_size, void* d_ws, size_t ws_size,
                              hipStream_t stream)
{
    const float* x       = (const float*)d_in[0];
    const float* Wi      = (const float*)d_in[1];
    const float* bi      = (const float*)d_in[2];
    const float* in_proj = (const float*)d_in[3];
    const float* conv_w  = (const float*)d_in[4];
    const float* conv_b  = (const float*)d_in[5];
    const float* x_proj  = (const float*)d_in[6];
    const float* dt_w    = (const float*)d_in[7];
    const float* dt_b    = (const float*)d_in[8];
    // d_in[9] = A_log: dead (L==1, h0==0)
    const float* Dp      = (const float*)d_in[10];
    const float* out_pw  = (const float*)d_in[11];
    const float* Wo      = (const float*)d_in[12];
    const float* bo      = (const float*)d_in[13];

    short* ws   = (short*)d_ws;
    short* xpad = ws;                                   // 4096*256
    short* WiT  = xpad + (size_t)NB * DM;               // 256*256
    short* ipT  = WiT + (size_t)DM * DM;                // 12*1024*256
    short* opT  = ipT + (size_t)NL * 2 * DI * DM;       // 12*256*512
    short* xpT  = opT + (size_t)NL * DM * DI;           // 12*64*512
    float* dtwT = (float*)(xpT + (size_t)NL * 64 * DI); // 12*512*16 fp32

    dim3 blk(256);

    conv_x<<<dim3(NB * DM / 256), blk, 0, stream>>>(x, xpad);
    conv_wt_t<<<dim3(4, 4, 1), blk, 0, stream>>>(Wi, WiT, IN_D, DM, DM, DM);
    conv_wt_t<<<dim3(4, 16, NL), blk, 0, stream>>>(in_proj, ipT, DM, 2 * DI, DM, 2 * DI);
    conv_wt_t<<<dim3(8, 4, NL), blk, 0, stream>>>(out_pw, opT, DI, DM, DI, DM);
    conv_wt_t<<<dim3(8, 1, NL), blk, 0, stream>>>(x_proj, xpT, DI, XPN, DI, 64);
    conv_dtw<<<dim3(DI * DTR / 256, NL), blk, 0, stream>>>(dt_w, dtwT);

    mamba_all<<<dim3(NB / 16), blk, 0, stream>>>(
        xpad, WiT, bi, ipT, opT, xpT, dtwT,
        conv_w, conv_b, dt_b, Dp, Wo, bo, (float*)d_out);
}

// Round 5
// 526.555 us; speedup vs baseline: 4.4241x; 1.4698x over previous
//
#include <hip/hip_runtime.h>
#include <math.h>

#define NB 4096
#define IN_D 230
#define DM 256
#define NL 12
#define DST 16
#define DI 512
#define DTR 16
#define XPN 48

typedef __attribute__((ext_vector_type(8))) short short8;
typedef __attribute__((ext_vector_type(4))) float floatx4;

__device__ __forceinline__ float silu_f(float x) { return x / (1.0f + expf(-x)); }
__device__ __forceinline__ float softplus_f(float x) { return (x > 20.0f) ? x : log1pf(expf(x)); }
__device__ __forceinline__ short f2bf(float x) {
    union { float f; unsigned u; } v; v.f = x;
    unsigned r = v.u + 0x7fff + ((v.u >> 16) & 1);
    return (short)(r >> 16);
}
__device__ __forceinline__ float bf2f(short s) {
    union { unsigned u; float f; } v; v.u = ((unsigned)(unsigned short)s) << 16;
    return v.f;
}

// ---------- conversion kernels (once per call) ----------

__global__ __launch_bounds__(256) void conv_x(const float* __restrict__ x, short* __restrict__ xp) {
    int idx = blockIdx.x * 256 + threadIdx.x;
    int r = idx >> 8, k = idx & 255;
    float v = (k < IN_D) ? x[(size_t)r * IN_D + k] : 0.0f;
    xp[idx] = f2bf(v);
}

// src [K x N] fp32 -> dst [Np x Kp] bf16 (dst[n][k]=src[k][n], zero-pad)
__global__ __launch_bounds__(256) void conv_wt_t(const float* __restrict__ src0, short* __restrict__ dst0,
                                                 int K, int N, int Kp, int Np) {
    const float* src = src0 + (size_t)blockIdx.z * K * N;
    short* dst = dst0 + (size_t)blockIdx.z * Np * Kp;
    __shared__ float t[64][65];
    const int k0 = blockIdx.x * 64, n0 = blockIdx.y * 64;
    const int r = threadIdx.x >> 6, c = threadIdx.x & 63;
#pragma unroll
    for (int i = 0; i < 16; i++) {
        int kk = k0 + i * 4 + r;
        int nn = n0 + c;
        float v = (kk < K && nn < N) ? src[(size_t)kk * N + nn] : 0.0f;
        t[i * 4 + r][c] = v;
    }
    __syncthreads();
#pragma unroll
    for (int i = 0; i < 16; i++) {
        int nn = n0 + i * 4 + r;
        int kk = k0 + c;
        dst[(size_t)nn * Kp + kk] = f2bf(t[c][i * 4 + r]);
    }
}

// dt_w [NL][16][512] fp32 -> dtwT [NL][512][16] fp32
__global__ __launch_bounds__(256) void conv_dtw(const float* __restrict__ src, float* __restrict__ dst) {
    int l = blockIdx.y;
    int idx = blockIdx.x * 256 + threadIdx.x;
    int d = idx >> 4, r = idx & 15;
    dst[(size_t)l * DI * DTR + idx] = src[(size_t)l * DTR * DI + r * DI + d];
}

// ---------- the whole network, fused: 256 wgs x 16 rows, 1024 threads (16 waves) ----------
__global__ __launch_bounds__(1024) void mamba_all(
    const short* __restrict__ xpad, const short* __restrict__ WiT,
    const float* __restrict__ bi,
    const short* __restrict__ ipT, const short* __restrict__ opT,
    const short* __restrict__ xpT, const float* __restrict__ dtwT,
    const float* __restrict__ conv_w, const float* __restrict__ conv_b,
    const float* __restrict__ dt_b, const float* __restrict__ Dp,
    const float* __restrict__ Wo, const float* __restrict__ bo,
    float* __restrict__ out)
{
    __shared__ short hs[16 * 264];     // h (16 x 256), stride 264
    __shared__ short xcs[16 * 520];    // xc, then y in place
    __shared__ short szs[16 * 520];    // silu(z)
    __shared__ float dbls[16 * 68];    // dbl fp32
    __shared__ float sbc[16];

    const int tid = threadIdx.x;
    const int w = tid >> 6, lane = tid & 63;
    const int q = lane >> 4, m16 = lane & 15;
    const int rb = blockIdx.x * 16;

    // stage 0: h = xpad @ WiT + bi   (each wave: 1 col-frag of 16)
    {
        floatx4 acc = (floatx4){0.f, 0.f, 0.f, 0.f};
        const short* Ap = xpad + (size_t)(rb + m16) * DM + q * 8;
        const short* Bp = WiT + (size_t)(w * 16 + m16) * DM + q * 8;
#pragma unroll
        for (int kk = 0; kk < DM; kk += 32) {
            short8 a = *(const short8*)(Ap + kk);
            short8 b = *(const short8*)(Bp + kk);
            acc = __builtin_amdgcn_mfma_f32_16x16x32_bf16(a, b, acc, 0, 0, 0);
        }
        int col = w * 16 + m16;
#pragma unroll
        for (int r = 0; r < 4; r++)
            hs[(q * 4 + r) * 264 + col] = f2bf(acc[r] + bi[col]);
    }
    __syncthreads();

    for (int l = 0; l < NL; l++) {
        const short* ip = ipT + (size_t)l * 2 * DI * DM;
        const short* xp = xpT + (size_t)l * 64 * DI;
        const short* op = opT + (size_t)l * DM * DI;
        const float* dw = dtwT + (size_t)l * DI * DTR;
        const float* cw = conv_w + (size_t)l * DI * 4;
        const float* cb = conv_b + (size_t)l * DI;
        const float* db = dt_b + (size_t)l * DI;
        const float* Dv = Dp + (size_t)l * DI;

        // stage 1: xz = h @ in_projT  (each wave: 4 col-frags = 64 cols of 1024)
        {
            floatx4 acc[4];
#pragma unroll
            for (int t = 0; t < 4; t++) acc[t] = (floatx4){0.f, 0.f, 0.f, 0.f};
            const short* Bp = ip + (size_t)(w * 64 + m16) * DM + q * 8;
            const short* Ar = hs + m16 * 264 + q * 8;
#pragma unroll 2
            for (int kk = 0; kk < DM; kk += 32) {
                short8 a = *(const short8*)(Ar + kk);
                short8 b[4];
#pragma unroll
                for (int t = 0; t < 4; t++) b[t] = *(const short8*)(Bp + (size_t)t * 16 * DM + kk);
#pragma unroll
                for (int t = 0; t < 4; t++)
                    acc[t] = __builtin_amdgcn_mfma_f32_16x16x32_bf16(a, b[t], acc[t], 0, 0, 0);
            }
            if (w < 8) {
#pragma unroll
                for (int t = 0; t < 4; t++)
#pragma unroll
                    for (int r = 0; r < 4; r++) {
                        int col = w * 64 + t * 16 + m16;
                        float v = silu_f(acc[t][r] * cw[col * 4 + 3] + cb[col]);
                        xcs[(q * 4 + r) * 520 + col] = f2bf(v);
                    }
            } else {
#pragma unroll
                for (int t = 0; t < 4; t++)
#pragma unroll
                    for (int r = 0; r < 4; r++) {
                        int col = (w - 8) * 64 + t * 16 + m16;
                        szs[(q * 4 + r) * 520 + col] = f2bf(silu_f(acc[t][r]));
                    }
            }
        }
        __syncthreads();

        // stage 2: dbl = xc @ x_projT  (waves 0..3, 1 frag each)
        if (w < 4) {
            floatx4 acc = (floatx4){0.f, 0.f, 0.f, 0.f};
            const short* Bp = xp + (size_t)(w * 16 + m16) * DI + q * 8;
            const short* Ar = xcs + m16 * 520 + q * 8;
#pragma unroll 8
            for (int kk = 0; kk < DI; kk += 32) {
                short8 a = *(const short8*)(Ar + kk);
                short8 b = *(const short8*)(Bp + kk);
                acc = __builtin_amdgcn_mfma_f32_16x16x32_bf16(a, b, acc, 0, 0, 0);
            }
#pragma unroll
            for (int r = 0; r < 4; r++)
                dbls[(q * 4 + r) * 68 + w * 16 + m16] = acc[r];
        }
        __syncthreads();

        if (tid < 16) {
            float bc = 0.0f;
#pragma unroll
            for (int s = 0; s < DST; s++)
                bc += dbls[tid * 68 + DTR + s] * dbls[tid * 68 + DTR + DST + s];
            sbc[tid] = bc;
        }
        __syncthreads();

        // stage 3: y = (softplus(dt)*bc + D) * xc * sz   (1024 threads: d = tid>>1, 8 rows each)
        {
            const int d = tid >> 1;
            const int r0 = (tid & 1) * 8;
            const float* wp = dw + (size_t)d * DTR;
            float wv[DTR];
#pragma unroll
            for (int r = 0; r < DTR; r++) wv[r] = wp[r];
            const float dbv = db[d], dvv = Dv[d];
#pragma unroll
            for (int i = 0; i < 8; i++) {
                int row = r0 + i;
                float a = dbv;
#pragma unroll
                for (int r = 0; r < DTR; r++) a += dbls[row * 68 + r] * wv[r];
                float dt = softplus_f(a);
                int off = row * 520 + d;
                float v = (dt * sbc[row] + dvv) * bf2f(xcs[off]) * bf2f(szs[off]);
                xcs[off] = f2bf(v);
            }
        }
        __syncthreads();

        // stage 4: h = y @ out_projT   (each wave: 1 col-frag of 16)
        {
            floatx4 acc = (floatx4){0.f, 0.f, 0.f, 0.f};
            const short* Bp = op + (size_t)(w * 16 + m16) * DI + q * 8;
            const short* Ar = xcs + m16 * 520 + q * 8;
#pragma unroll 8
            for (int kk = 0; kk < DI; kk += 32) {
                short8 a = *(const short8*)(Ar + kk);
                short8 b = *(const short8*)(Bp + kk);
                acc = __builtin_amdgcn_mfma_f32_16x16x32_bf16(a, b, acc, 0, 0, 0);
            }
            int col = w * 16 + m16;
#pragma unroll
            for (int r = 0; r < 4; r++)
                hs[(q * 4 + r) * 264 + col] = f2bf(acc[r]);
        }
        __syncthreads();
    }

    // final: wave w reduces row w
    {
        float s = 0.0f;
#pragma unroll
        for (int j = 0; j < 4; j++)
            s += bf2f(hs[w * 264 + lane * 4 + j]) * Wo[lane * 4 + j];
#pragma unroll
        for (int off = 32; off > 0; off >>= 1) s += __shfl_down(s, off);
        if (lane == 0) out[rb + w] = s + bo[0];
    }
}

extern "C" void kernel_launch(void* const* d_in, const int* in_sizes, int n_in,
                              void* d_out, int out_size, void* d_ws, size_t ws_size,
                              hipStream_t stream)
{
    const float* x       = (const float*)d_in[0];
    const float* Wi      = (const float*)d_in[1];
    const float* bi      = (const float*)d_in[2];
    const float* in_proj = (const float*)d_in[3];
    const float* conv_w  = (const float*)d_in[4];
    const float* conv_b  = (const float*)d_in[5];
    const float* x_proj  = (const float*)d_in[6];
    const float* dt_w    = (const float*)d_in[7];
    const float* dt_b    = (const float*)d_in[8];
    // d_in[9] = A_log: dead (L==1, h0==0)
    const float* Dp      = (const float*)d_in[10];
    const float* out_pw  = (const float*)d_in[11];
    const float* Wo      = (const float*)d_in[12];
    const float* bo      = (const float*)d_in[13];

    short* ws   = (short*)d_ws;
    short* xpad = ws;                                   // 4096*256
    short* WiT  = xpad + (size_t)NB * DM;               // 256*256
    short* ipT  = WiT + (size_t)DM * DM;                // 12*1024*256
    short* opT  = ipT + (size_t)NL * 2 * DI * DM;       // 12*256*512
    short* xpT  = opT + (size_t)NL * DM * DI;           // 12*64*512
    float* dtwT = (float*)(xpT + (size_t)NL * 64 * DI); // 12*512*16 fp32

    dim3 blk(256);

    conv_x<<<dim3(NB * DM / 256), blk, 0, stream>>>(x, xpad);
    conv_wt_t<<<dim3(4, 4, 1), blk, 0, stream>>>(Wi, WiT, IN_D, DM, DM, DM);
    conv_wt_t<<<dim3(4, 16, NL), blk, 0, stream>>>(in_proj, ipT, DM, 2 * DI, DM, 2 * DI);
    conv_wt_t<<<dim3(8, 4, NL), blk, 0, stream>>>(out_pw, opT, DI, DM, DI, DM);
    conv_wt_t<<<dim3(8, 1, NL), blk, 0, stream>>>(x_proj, xpT, DI, XPN, DI, 64);
    conv_dtw<<<dim3(DI * DTR / 256, NL), blk, 0, stream>>>(dt_w, dtwT);

    mamba_all<<<dim3(NB / 16), dim3(1024), 0, stream>>>(
        xpad, WiT, bi, ipT, opT, xpT, dtwT,
        conv_w, conv_b, dt_b, Dp, Wo, bo, (float*)d_out);
}